// Round 6
// baseline (513.472 us; speedup 1.0000x reference)
//
#include <hip/hip_runtime.h>

typedef unsigned int u32;
typedef unsigned short u16;
typedef __bf16 bf16x8 __attribute__((ext_vector_type(8)));
typedef __attribute__((ext_vector_type(4))) float f32x4;

#define MFMA16(a, b, c) __builtin_amdgcn_mfma_f32_16x16x32_bf16((a), (b), (c), 0, 0, 0)

static constexpr int SEQ = 1024, DIM = 512, NH = 8;

__device__ __forceinline__ u16 f2bf(float f) {
  u32 b = __float_as_uint(f);
  return (u16)((b + 0x7FFFu + ((b >> 16) & 1u)) >> 16);
}

__device__ __forceinline__ void g2l16(const void* g, void* l) {
  __builtin_amdgcn_global_load_lds(
      (const __attribute__((address_space(1))) u32*)g,
      (__attribute__((address_space(3))) u32*)l, 16, 0, 0);
}

// read 8 contiguous bf16 (16B) from a 64-col (128B-row) LDS tile with XOR-swizzled slots
__device__ __forceinline__ bf16x8 ldsr8(const u16* base, int row, int slot) {
  int phys = slot ^ (row & 7);
  return *(const bf16x8*)(base + row * 64 + phys * 8);
}

__global__ void cvt4(const float4* __restrict__ src, ushort4* __restrict__ dst, int n4) {
  int stride = gridDim.x * blockDim.x;
  for (int i = blockIdx.x * blockDim.x + threadIdx.x; i < n4; i += stride) {
    float4 v = src[i];
    ushort4 o;
    o.x = f2bf(v.x); o.y = f2bf(v.y); o.z = f2bf(v.z); o.w = f2bf(v.w);
    dst[i] = o;
  }
}

// all four 512x512 weights in one launch (blockIdx.y selects)
__global__ __launch_bounds__(256)
void cvtw(const float4* __restrict__ a, const float4* __restrict__ b,
          const float4* __restrict__ c, const float4* __restrict__ d,
          ushort4* __restrict__ oa, ushort4* __restrict__ ob,
          ushort4* __restrict__ oc, ushort4* __restrict__ od) {
  const int which = blockIdx.y;
  const float4* s = (which == 0) ? a : (which == 1) ? b : (which == 2) ? c : d;
  ushort4* o = (which == 0) ? oa : (which == 1) ? ob : (which == 2) ? oc : od;
  const int n4 = 512 * 512 / 4;
  int stride = gridDim.x * blockDim.x;
  for (int i = blockIdx.x * blockDim.x + threadIdx.x; i < n4; i += stride) {
    float4 v = s[i];
    ushort4 t;
    t.x = f2bf(v.x); t.y = f2bf(v.y); t.z = f2bf(v.z); t.w = f2bf(v.w);
    o[i] = t;
  }
}

// Vw: (16*1024 x 512) bf16 row-major -> Vt: [b][c][n] = [16][512][1024]
__global__ __launch_bounds__(256)
void transpose_v(const u16* __restrict__ Vw, u16* __restrict__ Vt) {
  __shared__ u16 t[64][80];
  const int ct = blockIdx.x;   // 8  (c tile)
  const int nt = blockIdx.y;   // 16 (n tile)
  const int b  = blockIdx.z;   // 16
  const int tid = threadIdx.x;

#pragma unroll
  for (int p = 0; p < 2; ++p) {
    int id = tid + p * 256;
    int row = id >> 3, ch = id & 7;
    bf16x8 v = *(const bf16x8*)(Vw + (size_t)(b * 1024 + nt * 64 + row) * 512 + ct * 64 + ch * 8);
    const u16* u = (const u16*)&v;
#pragma unroll
    for (int j = 0; j < 8; ++j) t[ch * 8 + j][row] = u[j];
  }
  __syncthreads();
#pragma unroll
  for (int p = 0; p < 2; ++p) {
    int id = tid + p * 256;
    int row = id >> 3, ch = id & 7;
    bf16x8 v = *(const bf16x8*)&t[row][ch * 8];
    *(bf16x8*)(Vt + (size_t)(b * 512 + ct * 64 + row) * 1024 + nt * 64 + ch * 8) = v;
  }
}

// C = A @ B^T, A: (M x 512) bf16 row-major, B: (512 x 512) bf16 row-major (N x K).
template <int OUT_F32>
__global__ __launch_bounds__(256)
void gemm_bt(const u16* __restrict__ A,
             const u16* __restrict__ B0, const u16* __restrict__ B1, const u16* __restrict__ B2,
             void* __restrict__ D0, void* __restrict__ D1, void* __restrict__ D2,
             float scale0) {
  __shared__ u16 As[128 * 64];
  __shared__ u16 Bs[128 * 64];

  const int tid = threadIdx.x;
  const int w = tid >> 6, l = tid & 63;
  const int sel = blockIdx.x >> 2;
  const u16* Bw = (sel == 0) ? B0 : ((sel == 1) ? B1 : B2);
  void* Dv = (sel == 0) ? D0 : ((sel == 1) ? D1 : D2);
  const float scale = (sel == 0) ? scale0 : 1.0f;
  const int n0 = (blockIdx.x & 3) * 128;
  const int m0 = blockIdx.y * 128;

  const int srow = l >> 3;
  const int sslot = (l & 7) ^ srow;
  const int wr = w >> 1, wc = w & 1;

  f32x4 acc[4][4] = {};

  for (int kk = 0; kk < 512; kk += 64) {
#pragma unroll
    for (int it = 0; it < 4; ++it) {
      int row = w * 32 + it * 8;
      g2l16(A + (size_t)(m0 + row + srow) * 512 + kk + sslot * 8, &As[row * 64]);
      g2l16(Bw + (size_t)(n0 + row + srow) * 512 + kk + sslot * 8, &Bs[row * 64]);
    }
    __syncthreads();

#pragma unroll
    for (int ks = 0; ks < 2; ++ks) {
      int slot = ks * 4 + (l >> 4);
      bf16x8 af[4], bfr[4];
#pragma unroll
      for (int m = 0; m < 4; ++m) af[m] = ldsr8(As, wr * 64 + m * 16 + (l & 15), slot);
#pragma unroll
      for (int n = 0; n < 4; ++n) bfr[n] = ldsr8(Bs, wc * 64 + n * 16 + (l & 15), slot);
#pragma unroll
      for (int m = 0; m < 4; ++m)
#pragma unroll
        for (int n = 0; n < 4; ++n)
          acc[m][n] = MFMA16(af[m], bfr[n], acc[m][n]);
    }
    __syncthreads();
  }

#pragma unroll
  for (int m = 0; m < 4; ++m) {
    int row = m0 + wr * 64 + m * 16 + ((l >> 4) << 2);
#pragma unroll
    for (int n = 0; n < 4; ++n) {
      int col = n0 + wc * 64 + n * 16 + (l & 15);
#pragma unroll
      for (int r = 0; r < 4; ++r) {
        float v = acc[m][n][r] * scale;
        if (OUT_F32)
          ((float*)Dv)[(size_t)(row + r) * 512 + col] = v;
        else
          ((u16*)Dv)[(size_t)(row + r) * 512 + col] = f2bf(v);
      }
    }
  }
}

// One iteration of the 2-phase pipelined attention loop (8-wave, 128 q-rows/block).
__device__ __forceinline__ void attn_iter(
    int kt, const u16* Kc, const u16* Vc, u16* Kn, u16* Vn,
    const float (&bcur)[16], float (&bnxt)[16],
    const u16* __restrict__ K, const u16* __restrict__ Vt,
    const float* bbase, int b, int h, int w, int l, int srow, int sslot,
    const bf16x8 (&qf)[2], u16* Pw, f32x4 (&o_acc)[4], float (&ps)[4]) {
  const bool notlast = (kt < 15);

  // (a) issue next tile's staging FIRST — HBM/L2 latency hides under compute
  if (notlast) {
    int row = w * 8;  // 8 waves cover 64 rows with one g2l16 each
    g2l16(K + (size_t)(b * SEQ + (kt + 1) * 64 + row + srow) * DIM + h * 64 + sslot * 8,
          &Kn[row * 64]);
    g2l16(Vt + (size_t)(b * 512 + h * 64 + row + srow) * SEQ + (kt + 1) * 64 + sslot * 8,
          &Vn[row * 64]);
  }

  // (b) S = bias + q@k^T : bias regs (prefetched last iter) as accumulator init
  f32x4 sacc[4];
#pragma unroll
  for (int nf = 0; nf < 4; ++nf)
#pragma unroll
    for (int r = 0; r < 4; ++r) sacc[nf][r] = bcur[nf * 4 + r];
  __builtin_amdgcn_s_setprio(1);
#pragma unroll
  for (int ks = 0; ks < 2; ++ks) {
    int slot = ks * 4 + (l >> 4);
#pragma unroll
    for (int nf = 0; nf < 4; ++nf) {
      bf16x8 kf = ldsr8(Kc, nf * 16 + (l & 15), slot);
      sacc[nf] = MFMA16(qf[ks], kf, sacc[nf]);
    }
  }
  __builtin_amdgcn_s_setprio(0);

  // (c) prefetch next tile's bias into registers (covered by exp+PV below)
  if (notlast) {
#pragma unroll
    for (int i = 0; i < 16; ++i)
      bnxt[i] = bbase[(size_t)(i & 3) * SEQ + (kt + 1) * 64 + (i >> 2) * 16];
  }

  // exp -> P (bf16) to per-wave LDS region (swizzled)
#pragma unroll
  for (int r = 0; r < 4; ++r) {
    int prow = ((l >> 4) << 2) + r;
#pragma unroll
    for (int nf = 0; nf < 4; ++nf) {
      float p = __expf(sacc[nf][r]);
      ps[r] += p;
      int col = nf * 16 + (l & 15);
      int slot = (col >> 3) ^ (prow & 7);
      Pw[prow * 64 + slot * 8 + (col & 7)] = f2bf(p);
    }
  }

  // O += P @ V
  __builtin_amdgcn_s_setprio(1);
#pragma unroll
  for (int ks = 0; ks < 2; ++ks) {
    bf16x8 pf = ldsr8(Pw, l & 15, ks * 4 + (l >> 4));
    int slot = ks * 4 + (l >> 4);
#pragma unroll
    for (int nf = 0; nf < 4; ++nf) {
      bf16x8 vf = ldsr8(Vc, nf * 16 + (l & 15), slot);
      o_acc[nf] = MFMA16(pf, vf, o_acc[nf]);
    }
  }
  __builtin_amdgcn_s_setprio(0);
  __syncthreads();  // next buffers staged + all reads of cur done
}

// Per block: one (b,h,qt2), 128 q-rows, 8 waves (each owns 16 q-rows).
// 2-phase double-buffered K/V staging; bias register-prefetch as MFMA C-init.
// LDS 48KB -> 3 blocks/CU = 24 waves/CU (75% occupancy).
__global__ __launch_bounds__(512, 6)
void attn_kern(const u16* __restrict__ Q, const u16* __restrict__ K,
               const u16* __restrict__ Vt, const float* __restrict__ bias,
               u16* __restrict__ O) {
  __shared__ u16 QPs[128 * 64];  // Q staging (16KB), then per-wave P scratch (8 x 2KB)
  __shared__ u16 K0s[64 * 64], V0s[64 * 64], K1s[64 * 64], V1s[64 * 64];

  const int tid = threadIdx.x;
  const int w = tid >> 6, l = tid & 63;
  const int b = blockIdx.x, h = blockIdx.y, qt = blockIdx.z;  // b fastest: bias L2 reuse

  const int srow = l >> 3;
  const int sslot = (l & 7) ^ srow;

  // prologue: stage Q (2 g2l16/wave) + tile0 K/V (1 each/wave); bias tile0 -> regs
#pragma unroll
  for (int it = 0; it < 2; ++it) {
    int row = w * 16 + it * 8;
    g2l16(Q + (size_t)(b * SEQ + qt * 128 + row + srow) * DIM + h * 64 + sslot * 8,
          &QPs[row * 64]);
  }
  {
    int row = w * 8;
    g2l16(K + (size_t)(b * SEQ + row + srow) * DIM + h * 64 + sslot * 8, &K0s[row * 64]);
    g2l16(Vt + (size_t)(b * 512 + h * 64 + row + srow) * SEQ + sslot * 8, &V0s[row * 64]);
  }
  const int qrow0 = qt * 128 + w * 16 + ((l >> 4) << 2);
  const float* bbase = bias + ((size_t)h * SEQ + qrow0) * SEQ + (l & 15);
  float biasA[16], biasB[16];
#pragma unroll
  for (int i = 0; i < 16; ++i) biasA[i] = bbase[(size_t)(i & 3) * SEQ + (i >> 2) * 16];
  __syncthreads();

  bf16x8 qf[2];
#pragma unroll
  for (int ks = 0; ks < 2; ++ks)
    qf[ks] = ldsr8(QPs, w * 16 + (l & 15), ks * 4 + (l >> 4));
  u16* Pw = &QPs[w * 16 * 64];  // each wave reads only its own 16 rows

  f32x4 o_acc[4] = {};
  float ps[4] = {};

  for (int kt = 0; kt < 16; kt += 2) {
    attn_iter(kt, K0s, V0s, K1s, V1s, biasA, biasB, K, Vt, bbase,
              b, h, w, l, srow, sslot, qf, Pw, o_acc, ps);
    attn_iter(kt + 1, K1s, V1s, K0s, V0s, biasB, biasA, K, Vt, bbase,
              b, h, w, l, srow, sslot, qf, Pw, o_acc, ps);
  }

  float rinv[4];
#pragma unroll
  for (int r = 0; r < 4; ++r) {
    float s = ps[r];
    s += __shfl_xor(s, 1); s += __shfl_xor(s, 2);
    s += __shfl_xor(s, 4); s += __shfl_xor(s, 8);
    rinv[r] = 1.0f / s;
  }
  const int orow0 = b * SEQ + qt * 128 + w * 16 + ((l >> 4) << 2);
#pragma unroll
  for (int nf = 0; nf < 4; ++nf) {
    int col = h * 64 + nf * 16 + (l & 15);
#pragma unroll
    for (int r = 0; r < 4; ++r)
      O[(size_t)(orow0 + r) * DIM + col] = f2bf(o_acc[nf][r] * rinv[r]);
  }
}

extern "C" void kernel_launch(void* const* d_in, const int* in_sizes, int n_in,
                              void* d_out, int out_size, void* d_ws, size_t ws_size,
                              hipStream_t stream) {
  const float* x  = (const float*)d_in[0];
  const float* pb = (const float*)d_in[1];
  const float* Wq = (const float*)d_in[2];
  const float* Wk = (const float*)d_in[3];
  const float* Wv = (const float*)d_in[4];
  const float* Wo = (const float*)d_in[5];

  const size_t MR = (size_t)16384 * 512;  // 8.39M elems (B*N x DIM)

  // Q,K (bf16) live inside d_out (exactly 2*MR*2 bytes). Buffer rotation keeps
  // ws at ~35.7MB: slot0: xb -> Vt ; slot1: Vw -> AO.
  u16* Qw = (u16*)d_out;
  u16* Kw = Qw + MR;

  char* ws = (char*)d_ws;
  u16* slot0 = (u16*)ws; ws += MR * 2;
  u16* slot1 = (u16*)ws; ws += MR * 2;
  u16* wqb = (u16*)ws; ws += 512 * 512 * 2;
  u16* wkb = (u16*)ws; ws += 512 * 512 * 2;
  u16* wvb = (u16*)ws; ws += 512 * 512 * 2;
  u16* wob = (u16*)ws; ws += 512 * 512 * 2;

  u16* xb = slot0;
  u16* Vw = slot1;
  u16* Vt = slot0;   // overwrites xb after it's dead
  u16* AO = slot1;   // overwrites Vw after it's dead

  cvt4<<<2048, 256, 0, stream>>>((const float4*)x, (ushort4*)xb, (int)(MR / 4));
  cvtw<<<dim3(64, 4), 256, 0, stream>>>((const float4*)Wq, (const float4*)Wk,
                                        (const float4*)Wv, (const float4*)Wo,
                                        (ushort4*)wqb, (ushort4*)wkb,
                                        (ushort4*)wvb, (ushort4*)wob);

  gemm_bt<0><<<dim3(12, 128), 256, 0, stream>>>(xb, wqb, wkb, wvb, Qw, Kw, Vw, 0.125f);

  transpose_v<<<dim3(8, 16, 16), 256, 0, stream>>>(Vw, Vt);

  attn_kern<<<dim3(16, NH, 8), 512, 0, stream>>>(Qw, Kw, Vt, pb, AO);

  gemm_bt<1><<<dim3(4, 128), 256, 0, stream>>>(AO, wob, wob, wob, d_out, d_out, d_out, 1.0f);
}

// Round 8
// 264.025 us; speedup vs baseline: 1.9448x; 1.9448x over previous
//
#include <hip/hip_runtime.h>

typedef unsigned int u32;
typedef unsigned short u16;
typedef __bf16 bf16x8 __attribute__((ext_vector_type(8)));
typedef __attribute__((ext_vector_type(4))) float f32x4;

#define MFMA16(a, b, c) __builtin_amdgcn_mfma_f32_16x16x32_bf16((a), (b), (c), 0, 0, 0)

static constexpr int SEQ = 1024, DIM = 512, NH = 8;

__device__ __forceinline__ u16 f2bf(float f) {
  u32 b = __float_as_uint(f);
  return (u16)((b + 0x7FFFu + ((b >> 16) & 1u)) >> 16);
}

__device__ __forceinline__ void g2l16(const void* g, void* l) {
  __builtin_amdgcn_global_load_lds(
      (const __attribute__((address_space(1))) u32*)g,
      (__attribute__((address_space(3))) u32*)l, 16, 0, 0);
}

// read 8 contiguous bf16 (16B) from a 64-col (128B-row) LDS tile with XOR-swizzled slots
__device__ __forceinline__ bf16x8 ldsr8(const u16* base, int row, int slot) {
  int phys = slot ^ (row & 7);
  return *(const bf16x8*)(base + row * 64 + phys * 8);
}

__global__ void cvt4(const float4* __restrict__ src, ushort4* __restrict__ dst, int n4) {
  int stride = gridDim.x * blockDim.x;
  for (int i = blockIdx.x * blockDim.x + threadIdx.x; i < n4; i += stride) {
    float4 v = src[i];
    ushort4 o;
    o.x = f2bf(v.x); o.y = f2bf(v.y); o.z = f2bf(v.z); o.w = f2bf(v.w);
    dst[i] = o;
  }
}

// all four 512x512 weights in one launch (blockIdx.y selects)
__global__ __launch_bounds__(256)
void cvtw(const float4* __restrict__ a, const float4* __restrict__ b,
          const float4* __restrict__ c, const float4* __restrict__ d,
          ushort4* __restrict__ oa, ushort4* __restrict__ ob,
          ushort4* __restrict__ oc, ushort4* __restrict__ od) {
  const int which = blockIdx.y;
  const float4* s = (which == 0) ? a : (which == 1) ? b : (which == 2) ? c : d;
  ushort4* o = (which == 0) ? oa : (which == 1) ? ob : (which == 2) ? oc : od;
  const int n4 = 512 * 512 / 4;
  int stride = gridDim.x * blockDim.x;
  for (int i = blockIdx.x * blockDim.x + threadIdx.x; i < n4; i += stride) {
    float4 v = s[i];
    ushort4 t;
    t.x = f2bf(v.x); t.y = f2bf(v.y); t.z = f2bf(v.z); t.w = f2bf(v.w);
    o[i] = t;
  }
}

// Vw: (16*1024 x 512) bf16 row-major -> Vt: [b][c][n] = [16][512][1024]
__global__ __launch_bounds__(256)
void transpose_v(const u16* __restrict__ Vw, u16* __restrict__ Vt) {
  __shared__ u16 t[64][80];
  const int ct = blockIdx.x;   // 8  (c tile)
  const int nt = blockIdx.y;   // 16 (n tile)
  const int b  = blockIdx.z;   // 16
  const int tid = threadIdx.x;

#pragma unroll
  for (int p = 0; p < 2; ++p) {
    int id = tid + p * 256;
    int row = id >> 3, ch = id & 7;
    bf16x8 v = *(const bf16x8*)(Vw + (size_t)(b * 1024 + nt * 64 + row) * 512 + ct * 64 + ch * 8);
    const u16* u = (const u16*)&v;
#pragma unroll
    for (int j = 0; j < 8; ++j) t[ch * 8 + j][row] = u[j];
  }
  __syncthreads();
#pragma unroll
  for (int p = 0; p < 2; ++p) {
    int id = tid + p * 256;
    int row = id >> 3, ch = id & 7;
    bf16x8 v = *(const bf16x8*)&t[row][ch * 8];
    *(bf16x8*)(Vt + (size_t)(b * 512 + ct * 64 + row) * 1024 + nt * 64 + ch * 8) = v;
  }
}

// C = A @ B^T, A: (M x 512) bf16 row-major, B: (512 x 512) bf16 row-major (N x K).
template <int OUT_F32>
__global__ __launch_bounds__(256)
void gemm_bt(const u16* __restrict__ A,
             const u16* __restrict__ B0, const u16* __restrict__ B1, const u16* __restrict__ B2,
             void* __restrict__ D0, void* __restrict__ D1, void* __restrict__ D2,
             float scale0) {
  __shared__ u16 As[128 * 64];
  __shared__ u16 Bs[128 * 64];

  const int tid = threadIdx.x;
  const int w = tid >> 6, l = tid & 63;
  const int sel = blockIdx.x >> 2;
  const u16* Bw = (sel == 0) ? B0 : ((sel == 1) ? B1 : B2);
  void* Dv = (sel == 0) ? D0 : ((sel == 1) ? D1 : D2);
  const float scale = (sel == 0) ? scale0 : 1.0f;
  const int n0 = (blockIdx.x & 3) * 128;
  const int m0 = blockIdx.y * 128;

  const int srow = l >> 3;
  const int sslot = (l & 7) ^ srow;
  const int wr = w >> 1, wc = w & 1;

  f32x4 acc[4][4] = {};

  for (int kk = 0; kk < 512; kk += 64) {
#pragma unroll
    for (int it = 0; it < 4; ++it) {
      int row = w * 32 + it * 8;
      g2l16(A + (size_t)(m0 + row + srow) * 512 + kk + sslot * 8, &As[row * 64]);
      g2l16(Bw + (size_t)(n0 + row + srow) * 512 + kk + sslot * 8, &Bs[row * 64]);
    }
    __syncthreads();

#pragma unroll
    for (int ks = 0; ks < 2; ++ks) {
      int slot = ks * 4 + (l >> 4);
      bf16x8 af[4], bfr[4];
#pragma unroll
      for (int m = 0; m < 4; ++m) af[m] = ldsr8(As, wr * 64 + m * 16 + (l & 15), slot);
#pragma unroll
      for (int n = 0; n < 4; ++n) bfr[n] = ldsr8(Bs, wc * 64 + n * 16 + (l & 15), slot);
#pragma unroll
      for (int m = 0; m < 4; ++m)
#pragma unroll
        for (int n = 0; n < 4; ++n)
          acc[m][n] = MFMA16(af[m], bfr[n], acc[m][n]);
    }
    __syncthreads();
  }

#pragma unroll
  for (int m = 0; m < 4; ++m) {
    int row = m0 + wr * 64 + m * 16 + ((l >> 4) << 2);
#pragma unroll
    for (int n = 0; n < 4; ++n) {
      int col = n0 + wc * 64 + n * 16 + (l & 15);
#pragma unroll
      for (int r = 0; r < 4; ++r) {
        float v = acc[m][n][r] * scale;
        if (OUT_F32)
          ((float*)Dv)[(size_t)(row + r) * 512 + col] = v;
        else
          ((u16*)Dv)[(size_t)(row + r) * 512 + col] = f2bf(v);
      }
    }
  }
}

// One iteration of the 2-phase pipelined attention loop (8-wave, 128 q-rows/block).
// bcur: bias f32x4[4] consumed as MFMA C-init; bnxt: prefetched for kt+1.
__device__ __forceinline__ void attn_iter(
    int kt, const u16* Kc, const u16* Vc, u16* Kn, u16* Vn,
    const f32x4 (&bcur)[4], f32x4 (&bnxt)[4],
    const u16* __restrict__ K, const u16* __restrict__ Vt,
    const float* bbase, int b, int h, int w, int l, int srow, int sslot,
    const bf16x8 (&qf)[2], u16* Pw, f32x4 (&o_acc)[4], float (&ps)[4]) {
  const bool notlast = (kt < 15);

  // (a) issue next tile's staging FIRST — HBM/L2 latency hides under compute
  if (notlast) {
    int row = w * 8;  // 8 waves cover 64 rows with one g2l16 each
    g2l16(K + (size_t)(b * SEQ + (kt + 1) * 64 + row + srow) * DIM + h * 64 + sslot * 8,
          &Kn[row * 64]);
    g2l16(Vt + (size_t)(b * 512 + h * 64 + row + srow) * SEQ + (kt + 1) * 64 + sslot * 8,
          &Vn[row * 64]);
  }

  // (b) S = bias + q@k^T : bias regs (prefetched last iter) as accumulator init
  f32x4 sacc[4];
#pragma unroll
  for (int nf = 0; nf < 4; ++nf) sacc[nf] = bcur[nf];
  __builtin_amdgcn_s_setprio(1);
#pragma unroll
  for (int ks = 0; ks < 2; ++ks) {
    int slot = ks * 4 + (l >> 4);
#pragma unroll
    for (int nf = 0; nf < 4; ++nf) {
      bf16x8 kf = ldsr8(Kc, nf * 16 + (l & 15), slot);
      sacc[nf] = MFMA16(qf[ks], kf, sacc[nf]);
    }
  }
  __builtin_amdgcn_s_setprio(0);

  // (c) prefetch next tile's bias into registers (covered by exp+PV below)
  if (notlast) {
#pragma unroll
    for (int nf = 0; nf < 4; ++nf)
#pragma unroll
      for (int r = 0; r < 4; ++r)
        bnxt[nf][r] = bbase[(size_t)r * SEQ + (kt + 1) * 64 + nf * 16];
  }

  // exp -> P (bf16) to per-wave LDS region (swizzled)
#pragma unroll
  for (int r = 0; r < 4; ++r) {
    int prow = ((l >> 4) << 2) + r;
#pragma unroll
    for (int nf = 0; nf < 4; ++nf) {
      float p = __expf(sacc[nf][r]);
      ps[r] += p;
      int col = nf * 16 + (l & 15);
      int slot = (col >> 3) ^ (prow & 7);
      Pw[prow * 64 + slot * 8 + (col & 7)] = f2bf(p);
    }
  }

  // O += P @ V
  __builtin_amdgcn_s_setprio(1);
#pragma unroll
  for (int ks = 0; ks < 2; ++ks) {
    bf16x8 pf = ldsr8(Pw, l & 15, ks * 4 + (l >> 4));
    int slot = ks * 4 + (l >> 4);
#pragma unroll
    for (int nf = 0; nf < 4; ++nf) {
      bf16x8 vf = ldsr8(Vc, nf * 16 + (l & 15), slot);
      o_acc[nf] = MFMA16(pf, vf, o_acc[nf]);
    }
  }
  __builtin_amdgcn_s_setprio(0);
  __syncthreads();  // next buffers staged + all reads of cur done
}

// Per block: one (b,h,qt), 128 q-rows, 8 waves (each owns 16 q-rows).
// 2-phase double-buffered K/V staging; bias register-prefetch as MFMA C-init.
// LDS 48KB -> 3 blocks/CU = 24 waves/CU. NOTE: no min-waves launch_bounds arg —
// round 6's (512,6) capped VGPRs to 40 and spilled the bias regs to scratch
// (WRITE_SIZE 493MB). Occupancy is LDS-limited anyway; the hint only hurts.
__global__ __launch_bounds__(512)
void attn_kern(const u16* __restrict__ Q, const u16* __restrict__ K,
               const u16* __restrict__ Vt, const float* __restrict__ bias,
               u16* __restrict__ O) {
  __shared__ u16 QPs[128 * 64];  // Q staging (16KB), then per-wave P scratch (8 x 2KB)
  __shared__ u16 K0s[64 * 64], V0s[64 * 64], K1s[64 * 64], V1s[64 * 64];

  const int tid = threadIdx.x;
  const int w = tid >> 6, l = tid & 63;
  const int b = blockIdx.x, h = blockIdx.y, qt = blockIdx.z;  // b fastest: bias L2 reuse

  const int srow = l >> 3;
  const int sslot = (l & 7) ^ srow;

  // prologue: stage Q (2 g2l16/wave) + tile0 K/V (1 each/wave); bias tile0 -> regs
#pragma unroll
  for (int it = 0; it < 2; ++it) {
    int row = w * 16 + it * 8;
    g2l16(Q + (size_t)(b * SEQ + qt * 128 + row + srow) * DIM + h * 64 + sslot * 8,
          &QPs[row * 64]);
  }
  {
    int row = w * 8;
    g2l16(K + (size_t)(b * SEQ + row + srow) * DIM + h * 64 + sslot * 8, &K0s[row * 64]);
    g2l16(Vt + (size_t)(b * 512 + h * 64 + row + srow) * SEQ + sslot * 8, &V0s[row * 64]);
  }
  const int qrow0 = qt * 128 + w * 16 + ((l >> 4) << 2);
  const float* bbase = bias + ((size_t)h * SEQ + qrow0) * SEQ + (l & 15);
  f32x4 biasA[4], biasB[4];
#pragma unroll
  for (int nf = 0; nf < 4; ++nf)
#pragma unroll
    for (int r = 0; r < 4; ++r)
      biasA[nf][r] = bbase[(size_t)r * SEQ + nf * 16];
  __syncthreads();

  bf16x8 qf[2];
#pragma unroll
  for (int ks = 0; ks < 2; ++ks)
    qf[ks] = ldsr8(QPs, w * 16 + (l & 15), ks * 4 + (l >> 4));
  u16* Pw = &QPs[w * 16 * 64];  // each wave reads only its own 16 rows

  f32x4 o_acc[4] = {};
  float ps[4] = {};

  for (int kt = 0; kt < 16; kt += 2) {
    attn_iter(kt, K0s, V0s, K1s, V1s, biasA, biasB, K, Vt, bbase,
              b, h, w, l, srow, sslot, qf, Pw, o_acc, ps);
    attn_iter(kt + 1, K1s, V1s, K0s, V0s, biasB, biasA, K, Vt, bbase,
              b, h, w, l, srow, sslot, qf, Pw, o_acc, ps);
  }

  float rinv[4];
#pragma unroll
  for (int r = 0; r < 4; ++r) {
    float s = ps[r];
    s += __shfl_xor(s, 1); s += __shfl_xor(s, 2);
    s += __shfl_xor(s, 4); s += __shfl_xor(s, 8);
    rinv[r] = 1.0f / s;
  }
  const int orow0 = b * SEQ + qt * 128 + w * 16 + ((l >> 4) << 2);
#pragma unroll
  for (int nf = 0; nf < 4; ++nf) {
    int col = h * 64 + nf * 16 + (l & 15);
#pragma unroll
    for (int r = 0; r < 4; ++r)
      O[(size_t)(orow0 + r) * DIM + col] = f2bf(o_acc[nf][r] * rinv[r]);
  }
}

extern "C" void kernel_launch(void* const* d_in, const int* in_sizes, int n_in,
                              void* d_out, int out_size, void* d_ws, size_t ws_size,
                              hipStream_t stream) {
  const float* x  = (const float*)d_in[0];
  const float* pb = (const float*)d_in[1];
  const float* Wq = (const float*)d_in[2];
  const float* Wk = (const float*)d_in[3];
  const float* Wv = (const float*)d_in[4];
  const float* Wo = (const float*)d_in[5];

  const size_t MR = (size_t)16384 * 512;  // 8.39M elems (B*N x DIM)

  // Q,K (bf16) live inside d_out (exactly 2*MR*2 bytes). Buffer rotation keeps
  // ws at ~35.7MB: slot0: xb -> Vt ; slot1: Vw -> AO.
  u16* Qw = (u16*)d_out;
  u16* Kw = Qw + MR;

  char* ws = (char*)d_ws;
  u16* slot0 = (u16*)ws; ws += MR * 2;
  u16* slot1 = (u16*)ws; ws += MR * 2;
  u16* wqb = (u16*)ws; ws += 512 * 512 * 2;
  u16* wkb = (u16*)ws; ws += 512 * 512 * 2;
  u16* wvb = (u16*)ws; ws += 512 * 512 * 2;
  u16* wob = (u16*)ws; ws += 512 * 512 * 2;

  u16* xb = slot0;
  u16* Vw = slot1;
  u16* Vt = slot0;   // overwrites xb after it's dead
  u16* AO = slot1;   // overwrites Vw after it's dead

  cvt4<<<2048, 256, 0, stream>>>((const float4*)x, (ushort4*)xb, (int)(MR / 4));
  cvtw<<<dim3(64, 4), 256, 0, stream>>>((const float4*)Wq, (const float4*)Wk,
                                        (const float4*)Wv, (const float4*)Wo,
                                        (ushort4*)wqb, (ushort4*)wkb,
                                        (ushort4*)wvb, (ushort4*)wob);

  gemm_bt<0><<<dim3(12, 128), 256, 0, stream>>>(xb, wqb, wkb, wvb, Qw, Kw, Vw, 0.125f);

  transpose_v<<<dim3(8, 16, 16), 256, 0, stream>>>(Vw, Vt);

  attn_kern<<<dim3(16, NH, 8), 512, 0, stream>>>(Qw, Kw, Vt, pb, AO);

  gemm_bt<1><<<dim3(4, 128), 256, 0, stream>>>(AO, wob, wob, wob, d_out, d_out, d_out, 1.0f);
}

// Round 10
// 262.164 us; speedup vs baseline: 1.9586x; 1.0071x over previous
//
#include <hip/hip_runtime.h>

typedef unsigned int u32;
typedef unsigned short u16;
typedef __bf16 bf16x8 __attribute__((ext_vector_type(8)));
typedef __attribute__((ext_vector_type(4))) float f32x4;

#define MFMA16(a, b, c) __builtin_amdgcn_mfma_f32_16x16x32_bf16((a), (b), (c), 0, 0, 0)

static constexpr int SEQ = 1024, DIM = 512, NH = 8;

__device__ __forceinline__ u16 f2bf(float f) {
  u32 b = __float_as_uint(f);
  return (u16)((b + 0x7FFFu + ((b >> 16) & 1u)) >> 16);
}

__device__ __forceinline__ void g2l16(const void* g, void* l) {
  __builtin_amdgcn_global_load_lds(
      (const __attribute__((address_space(1))) u32*)g,
      (__attribute__((address_space(3))) u32*)l, 16, 0, 0);
}

// read 8 contiguous bf16 (16B) from a 64-col (128B-row) LDS tile with XOR-swizzled slots
__device__ __forceinline__ bf16x8 ldsr8(const u16* base, int row, int slot) {
  int phys = slot ^ (row & 7);
  return *(const bf16x8*)(base + row * 64 + phys * 8);
}

__global__ void cvt4(const float4* __restrict__ src, ushort4* __restrict__ dst, int n4) {
  int stride = gridDim.x * blockDim.x;
  for (int i = blockIdx.x * blockDim.x + threadIdx.x; i < n4; i += stride) {
    float4 v = src[i];
    ushort4 o;
    o.x = f2bf(v.x); o.y = f2bf(v.y); o.z = f2bf(v.z); o.w = f2bf(v.w);
    dst[i] = o;
  }
}

// all four 512x512 weights in one launch (blockIdx.y selects)
__global__ __launch_bounds__(256)
void cvtw(const float4* __restrict__ a, const float4* __restrict__ b,
          const float4* __restrict__ c, const float4* __restrict__ d,
          ushort4* __restrict__ oa, ushort4* __restrict__ ob,
          ushort4* __restrict__ oc, ushort4* __restrict__ od) {
  const int which = blockIdx.y;
  const float4* s = (which == 0) ? a : (which == 1) ? b : (which == 2) ? c : d;
  ushort4* o = (which == 0) ? oa : (which == 1) ? ob : (which == 2) ? oc : od;
  const int n4 = 512 * 512 / 4;
  int stride = gridDim.x * blockDim.x;
  for (int i = blockIdx.x * blockDim.x + threadIdx.x; i < n4; i += stride) {
    float4 v = s[i];
    ushort4 t;
    t.x = f2bf(v.x); t.y = f2bf(v.y); t.z = f2bf(v.z); t.w = f2bf(v.w);
    o[i] = t;
  }
}

// Vw: (16*1024 x 512) bf16 row-major -> Vt: [b][c][n] = [16][512][1024]
__global__ __launch_bounds__(256)
void transpose_v(const u16* __restrict__ Vw, u16* __restrict__ Vt) {
  __shared__ u16 t[64][80];
  const int ct = blockIdx.x;   // 8  (c tile)
  const int nt = blockIdx.y;   // 16 (n tile)
  const int b  = blockIdx.z;   // 16
  const int tid = threadIdx.x;

#pragma unroll
  for (int p = 0; p < 2; ++p) {
    int id = tid + p * 256;
    int row = id >> 3, ch = id & 7;
    bf16x8 v = *(const bf16x8*)(Vw + (size_t)(b * 1024 + nt * 64 + row) * 512 + ct * 64 + ch * 8);
    const u16* u = (const u16*)&v;
#pragma unroll
    for (int j = 0; j < 8; ++j) t[ch * 8 + j][row] = u[j];
  }
  __syncthreads();
#pragma unroll
  for (int p = 0; p < 2; ++p) {
    int id = tid + p * 256;
    int row = id >> 3, ch = id & 7;
    bf16x8 v = *(const bf16x8*)&t[row][ch * 8];
    *(bf16x8*)(Vt + (size_t)(b * 512 + ct * 64 + row) * 1024 + nt * 64 + ch * 8) = v;
  }
}

// C = A @ B^T, A: (M x 512) bf16 row-major, B: (512 x 512) bf16 row-major (N x K).
template <int OUT_F32>
__global__ __launch_bounds__(256)
void gemm_bt(const u16* __restrict__ A,
             const u16* __restrict__ B0, const u16* __restrict__ B1, const u16* __restrict__ B2,
             void* __restrict__ D0, void* __restrict__ D1, void* __restrict__ D2,
             float scale0) {
  __shared__ u16 As[128 * 64];
  __shared__ u16 Bs[128 * 64];

  const int tid = threadIdx.x;
  const int w = tid >> 6, l = tid & 63;
  const int sel = blockIdx.x >> 2;
  const u16* Bw = (sel == 0) ? B0 : ((sel == 1) ? B1 : B2);
  void* Dv = (sel == 0) ? D0 : ((sel == 1) ? D1 : D2);
  const float scale = (sel == 0) ? scale0 : 1.0f;
  const int n0 = (blockIdx.x & 3) * 128;
  const int m0 = blockIdx.y * 128;

  const int srow = l >> 3;
  const int sslot = (l & 7) ^ srow;
  const int wr = w >> 1, wc = w & 1;

  f32x4 acc[4][4] = {};

  for (int kk = 0; kk < 512; kk += 64) {
#pragma unroll
    for (int it = 0; it < 4; ++it) {
      int row = w * 32 + it * 8;
      g2l16(A + (size_t)(m0 + row + srow) * 512 + kk + sslot * 8, &As[row * 64]);
      g2l16(Bw + (size_t)(n0 + row + srow) * 512 + kk + sslot * 8, &Bs[row * 64]);
    }
    __syncthreads();

#pragma unroll
    for (int ks = 0; ks < 2; ++ks) {
      int slot = ks * 4 + (l >> 4);
      bf16x8 af[4], bfr[4];
#pragma unroll
      for (int m = 0; m < 4; ++m) af[m] = ldsr8(As, wr * 64 + m * 16 + (l & 15), slot);
#pragma unroll
      for (int n = 0; n < 4; ++n) bfr[n] = ldsr8(Bs, wc * 64 + n * 16 + (l & 15), slot);
#pragma unroll
      for (int m = 0; m < 4; ++m)
#pragma unroll
        for (int n = 0; n < 4; ++n)
          acc[m][n] = MFMA16(af[m], bfr[n], acc[m][n]);
    }
    __syncthreads();
  }

#pragma unroll
  for (int m = 0; m < 4; ++m) {
    int row = m0 + wr * 64 + m * 16 + ((l >> 4) << 2);
#pragma unroll
    for (int n = 0; n < 4; ++n) {
      int col = n0 + wc * 64 + n * 16 + (l & 15);
#pragma unroll
      for (int r = 0; r < 4; ++r) {
        float v = acc[m][n][r] * scale;
        if (OUT_F32)
          ((float*)Dv)[(size_t)(row + r) * 512 + col] = v;
        else
          ((u16*)Dv)[(size_t)(row + r) * 512 + col] = f2bf(v);
      }
    }
  }
}

// One iteration of the 2-phase pipelined attention loop (8-wave, 128 q-rows/block).
// bcur: bias f32x4[4] consumed as MFMA C-init; bnxt: prefetched for kt+1.
__device__ __forceinline__ void attn_iter(
    int kt, const u16* Kc, const u16* Vc, u16* Kn, u16* Vn,
    const f32x4 (&bcur)[4], f32x4 (&bnxt)[4],
    const u16* __restrict__ K, const u16* __restrict__ Vt,
    const float* bbase, int b, int h, int w, int l, int srow, int sslot,
    const bf16x8 (&qf)[2], u16* Pw, f32x4 (&o_acc)[4], float (&ps)[4]) {
  const bool notlast = (kt < 15);

  // (a) issue next tile's staging FIRST — HBM/L2 latency hides under compute
  if (notlast) {
    int row = w * 8;  // 8 waves cover 64 rows with one g2l16 each
    g2l16(K + (size_t)(b * SEQ + (kt + 1) * 64 + row + srow) * DIM + h * 64 + sslot * 8,
          &Kn[row * 64]);
    g2l16(Vt + (size_t)(b * 512 + h * 64 + row + srow) * SEQ + (kt + 1) * 64 + sslot * 8,
          &Vn[row * 64]);
  }

  // (b) S = bias + q@k^T : bias regs (prefetched last iter) as accumulator init
  f32x4 sacc[4];
#pragma unroll
  for (int nf = 0; nf < 4; ++nf) sacc[nf] = bcur[nf];
  __builtin_amdgcn_s_setprio(1);
#pragma unroll
  for (int ks = 0; ks < 2; ++ks) {
    int slot = ks * 4 + (l >> 4);
#pragma unroll
    for (int nf = 0; nf < 4; ++nf) {
      bf16x8 kf = ldsr8(Kc, nf * 16 + (l & 15), slot);
      sacc[nf] = MFMA16(qf[ks], kf, sacc[nf]);
    }
  }
  __builtin_amdgcn_s_setprio(0);

  // (c) prefetch next tile's bias into registers (covered by exp+PV below)
  if (notlast) {
#pragma unroll
    for (int nf = 0; nf < 4; ++nf)
#pragma unroll
      for (int r = 0; r < 4; ++r)
        bnxt[nf][r] = bbase[(size_t)r * SEQ + (kt + 1) * 64 + nf * 16];
  }

  // exp -> P (bf16) to per-wave LDS region (swizzled)
#pragma unroll
  for (int r = 0; r < 4; ++r) {
    int prow = ((l >> 4) << 2) + r;
#pragma unroll
    for (int nf = 0; nf < 4; ++nf) {
      float p = __expf(sacc[nf][r]);
      ps[r] += p;
      int col = nf * 16 + (l & 15);
      int slot = (col >> 3) ^ (prow & 7);
      Pw[prow * 64 + slot * 8 + (col & 7)] = f2bf(p);
    }
  }

  // O += P @ V
  __builtin_amdgcn_s_setprio(1);
#pragma unroll
  for (int ks = 0; ks < 2; ++ks) {
    bf16x8 pf = ldsr8(Pw, l & 15, ks * 4 + (l >> 4));
    int slot = ks * 4 + (l >> 4);
#pragma unroll
    for (int nf = 0; nf < 4; ++nf) {
      bf16x8 vf = ldsr8(Vc, nf * 16 + (l & 15), slot);
      o_acc[nf] = MFMA16(pf, vf, o_acc[nf]);
    }
  }
  __builtin_amdgcn_s_setprio(0);
  __syncthreads();  // next buffers staged + all reads of cur done
}

// Per block: one (b,h,qt), 128 q-rows, 8 waves (each owns 16 q-rows).
// 1-D grid with XCD-aware decode: id%8 = h (8 XCDs <-> 8 heads), b fastest
// within an XCD, qt slowest. Consecutive blocks round-robin XCDs, so each XCD
// owns one head: its L2 holds that head's K/V (16 b x 256KB = 4MB = L2) and
// bias slices get 16x same-L2 reuse. Cuts HBM fetch ~2.5x vs (b,h,qt) 3-D grid.
__global__ __launch_bounds__(512)
void attn_kern(const u16* __restrict__ Q, const u16* __restrict__ K,
               const u16* __restrict__ Vt, const float* __restrict__ bias,
               u16* __restrict__ O) {
  __shared__ u16 QPs[128 * 64];  // Q staging (16KB), then per-wave P scratch (8 x 2KB)
  __shared__ u16 K0s[64 * 64], V0s[64 * 64], K1s[64 * 64], V1s[64 * 64];

  const int tid = threadIdx.x;
  const int w = tid >> 6, l = tid & 63;
  const int id = blockIdx.x;
  const int h = id & 7;
  const int b = (id >> 3) & 15;
  const int qt = id >> 7;

  const int srow = l >> 3;
  const int sslot = (l & 7) ^ srow;

  // prologue: stage Q (2 g2l16/wave) + tile0 K/V (1 each/wave); bias tile0 -> regs
#pragma unroll
  for (int it = 0; it < 2; ++it) {
    int row = w * 16 + it * 8;
    g2l16(Q + (size_t)(b * SEQ + qt * 128 + row + srow) * DIM + h * 64 + sslot * 8,
          &QPs[row * 64]);
  }
  {
    int row = w * 8;
    g2l16(K + (size_t)(b * SEQ + row + srow) * DIM + h * 64 + sslot * 8, &K0s[row * 64]);
    g2l16(Vt + (size_t)(b * 512 + h * 64 + row + srow) * SEQ + sslot * 8, &V0s[row * 64]);
  }
  const int qrow0 = qt * 128 + w * 16 + ((l >> 4) << 2);
  const float* bbase = bias + ((size_t)h * SEQ + qrow0) * SEQ + (l & 15);
  f32x4 biasA[4], biasB[4];
#pragma unroll
  for (int nf = 0; nf < 4; ++nf)
#pragma unroll
    for (int r = 0; r < 4; ++r)
      biasA[nf][r] = bbase[(size_t)r * SEQ + nf * 16];
  __syncthreads();

  bf16x8 qf[2];
#pragma unroll
  for (int ks = 0; ks < 2; ++ks)
    qf[ks] = ldsr8(QPs, w * 16 + (l & 15), ks * 4 + (l >> 4));
  u16* Pw = &QPs[w * 16 * 64];  // each wave reads only its own 16 rows

  f32x4 o_acc[4] = {};
  float ps[4] = {};

  for (int kt = 0; kt < 16; kt += 2) {
    attn_iter(kt, K0s, V0s, K1s, V1s, biasA, biasB, K, Vt, bbase,
              b, h, w, l, srow, sslot, qf, Pw, o_acc, ps);
    attn_iter(kt + 1, K1s, V1s, K0s, V0s, biasB, biasA, K, Vt, bbase,
              b, h, w, l, srow, sslot, qf, Pw, o_acc, ps);
  }

  float rinv[4];
#pragma unroll
  for (int r = 0; r < 4; ++r) {
    float s = ps[r];
    s += __shfl_xor(s, 1); s += __shfl_xor(s, 2);
    s += __shfl_xor(s, 4); s += __shfl_xor(s, 8);
    rinv[r] = 1.0f / s;
  }
  const int orow0 = b * SEQ + qt * 128 + w * 16 + ((l >> 4) << 2);
#pragma unroll
  for (int nf = 0; nf < 4; ++nf) {
    int col = h * 64 + nf * 16 + (l & 15);
#pragma unroll
    for (int r = 0; r < 4; ++r)
      O[(size_t)(orow0 + r) * DIM + col] = f2bf(o_acc[nf][r] * rinv[r]);
  }
}

extern "C" void kernel_launch(void* const* d_in, const int* in_sizes, int n_in,
                              void* d_out, int out_size, void* d_ws, size_t ws_size,
                              hipStream_t stream) {
  const float* x  = (const float*)d_in[0];
  const float* pb = (const float*)d_in[1];
  const float* Wq = (const float*)d_in[2];
  const float* Wk = (const float*)d_in[3];
  const float* Wv = (const float*)d_in[4];
  const float* Wo = (const float*)d_in[5];

  const size_t MR = (size_t)16384 * 512;  // 8.39M elems (B*N x DIM)

  // Q,K (bf16) live inside d_out (exactly 2*MR*2 bytes). Buffer rotation keeps
  // ws at ~35.7MB: slot0: xb -> Vt ; slot1: Vw -> AO.
  u16* Qw = (u16*)d_out;
  u16* Kw = Qw + MR;

  char* ws = (char*)d_ws;
  u16* slot0 = (u16*)ws; ws += MR * 2;
  u16* slot1 = (u16*)ws; ws += MR * 2;
  u16* wqb = (u16*)ws; ws += 512 * 512 * 2;
  u16* wkb = (u16*)ws; ws += 512 * 512 * 2;
  u16* wvb = (u16*)ws; ws += 512 * 512 * 2;
  u16* wob = (u16*)ws; ws += 512 * 512 * 2;

  u16* xb = slot0;
  u16* Vw = slot1;
  u16* Vt = slot0;   // overwrites xb after it's dead
  u16* AO = slot1;   // overwrites Vw after it's dead

  cvt4<<<2048, 256, 0, stream>>>((const float4*)x, (ushort4*)xb, (int)(MR / 4));
  cvtw<<<dim3(64, 4), 256, 0, stream>>>((const float4*)Wq, (const float4*)Wk,
                                        (const float4*)Wv, (const float4*)Wo,
                                        (ushort4*)wqb, (ushort4*)wkb,
                                        (ushort4*)wvb, (ushort4*)wob);

  gemm_bt<0><<<dim3(12, 128), 256, 0, stream>>>(xb, wqb, wkb, wvb, Qw, Kw, Vw, 0.125f);

  transpose_v<<<dim3(8, 16, 16), 256, 0, stream>>>(Vw, Vt);

  attn_kern<<<dim3(1024), 512, 0, stream>>>(Qw, Kw, Vt, pb, AO);

  gemm_bt<1><<<dim3(4, 128), 256, 0, stream>>>(AO, wob, wob, wob, d_out, d_out, d_out, 1.0f);
}

// Round 11
// 246.030 us; speedup vs baseline: 2.0870x; 1.0656x over previous
//
#include <hip/hip_runtime.h>

typedef unsigned int u32;
typedef unsigned short u16;
typedef __bf16 bf16x8 __attribute__((ext_vector_type(8)));
typedef __attribute__((ext_vector_type(4))) float f32x4;

#define MFMA16(a, b, c) __builtin_amdgcn_mfma_f32_16x16x32_bf16((a), (b), (c), 0, 0, 0)

static constexpr int SEQ = 1024, DIM = 512, NH = 8;

__device__ __forceinline__ u16 f2bf(float f) {
  u32 b = __float_as_uint(f);
  return (u16)((b + 0x7FFFu + ((b >> 16) & 1u)) >> 16);
}

__device__ __forceinline__ void g2l16(const void* g, void* l) {
  __builtin_amdgcn_global_load_lds(
      (const __attribute__((address_space(1))) u32*)g,
      (__attribute__((address_space(3))) u32*)l, 16, 0, 0);
}

// read 8 contiguous bf16 (16B) from a 64-col (128B-row) LDS tile with XOR-swizzled slots
__device__ __forceinline__ bf16x8 ldsr8(const u16* base, int row, int slot) {
  int phys = slot ^ (row & 7);
  return *(const bf16x8*)(base + row * 64 + phys * 8);
}

__global__ void cvt4(const float4* __restrict__ src, ushort4* __restrict__ dst, int n4) {
  int stride = gridDim.x * blockDim.x;
  for (int i = blockIdx.x * blockDim.x + threadIdx.x; i < n4; i += stride) {
    float4 v = src[i];
    ushort4 o;
    o.x = f2bf(v.x); o.y = f2bf(v.y); o.z = f2bf(v.z); o.w = f2bf(v.w);
    dst[i] = o;
  }
}

// all four 512x512 weights in one launch (blockIdx.y selects)
__global__ __launch_bounds__(256)
void cvtw(const float4* __restrict__ a, const float4* __restrict__ b,
          const float4* __restrict__ c, const float4* __restrict__ d,
          ushort4* __restrict__ oa, ushort4* __restrict__ ob,
          ushort4* __restrict__ oc, ushort4* __restrict__ od) {
  const int which = blockIdx.y;
  const float4* s = (which == 0) ? a : (which == 1) ? b : (which == 2) ? c : d;
  ushort4* o = (which == 0) ? oa : (which == 1) ? ob : (which == 2) ? oc : od;
  const int n4 = 512 * 512 / 4;
  int stride = gridDim.x * blockDim.x;
  for (int i = blockIdx.x * blockDim.x + threadIdx.x; i < n4; i += stride) {
    float4 v = s[i];
    ushort4 t;
    t.x = f2bf(v.x); t.y = f2bf(v.y); t.z = f2bf(v.z); t.w = f2bf(v.w);
    o[i] = t;
  }
}

// Vw: (16*1024 x 512) bf16 row-major -> Vt: [b][c][n] = [16][512][1024]
__global__ __launch_bounds__(256)
void transpose_v(const u16* __restrict__ Vw, u16* __restrict__ Vt) {
  __shared__ u16 t[64][80];
  const int ct = blockIdx.x;   // 8  (c tile)
  const int nt = blockIdx.y;   // 16 (n tile)
  const int b  = blockIdx.z;   // 16
  const int tid = threadIdx.x;

#pragma unroll
  for (int p = 0; p < 2; ++p) {
    int id = tid + p * 256;
    int row = id >> 3, ch = id & 7;
    bf16x8 v = *(const bf16x8*)(Vw + (size_t)(b * 1024 + nt * 64 + row) * 512 + ct * 64 + ch * 8);
    const u16* u = (const u16*)&v;
#pragma unroll
    for (int j = 0; j < 8; ++j) t[ch * 8 + j][row] = u[j];
  }
  __syncthreads();
#pragma unroll
  for (int p = 0; p < 2; ++p) {
    int id = tid + p * 256;
    int row = id >> 3, ch = id & 7;
    bf16x8 v = *(const bf16x8*)&t[row][ch * 8];
    *(bf16x8*)(Vt + (size_t)(b * 512 + ct * 64 + row) * 1024 + nt * 64 + ch * 8) = v;
  }
}

// C = A @ B^T, A: (M x 512) bf16 row-major, B: (512 x 512) bf16 row-major (N x K).
template <int OUT_F32>
__global__ __launch_bounds__(256)
void gemm_bt(const u16* __restrict__ A,
             const u16* __restrict__ B0, const u16* __restrict__ B1, const u16* __restrict__ B2,
             void* __restrict__ D0, void* __restrict__ D1, void* __restrict__ D2,
             float scale0) {
  __shared__ u16 As[128 * 64];
  __shared__ u16 Bs[128 * 64];

  const int tid = threadIdx.x;
  const int w = tid >> 6, l = tid & 63;
  const int sel = blockIdx.x >> 2;
  const u16* Bw = (sel == 0) ? B0 : ((sel == 1) ? B1 : B2);
  void* Dv = (sel == 0) ? D0 : ((sel == 1) ? D1 : D2);
  const float scale = (sel == 0) ? scale0 : 1.0f;
  const int n0 = (blockIdx.x & 3) * 128;
  const int m0 = blockIdx.y * 128;

  const int srow = l >> 3;
  const int sslot = (l & 7) ^ srow;
  const int wr = w >> 1, wc = w & 1;

  f32x4 acc[4][4] = {};

  for (int kk = 0; kk < 512; kk += 64) {
#pragma unroll
    for (int it = 0; it < 4; ++it) {
      int row = w * 32 + it * 8;
      g2l16(A + (size_t)(m0 + row + srow) * 512 + kk + sslot * 8, &As[row * 64]);
      g2l16(Bw + (size_t)(n0 + row + srow) * 512 + kk + sslot * 8, &Bs[row * 64]);
    }
    __syncthreads();

#pragma unroll
    for (int ks = 0; ks < 2; ++ks) {
      int slot = ks * 4 + (l >> 4);
      bf16x8 af[4], bfr[4];
#pragma unroll
      for (int m = 0; m < 4; ++m) af[m] = ldsr8(As, wr * 64 + m * 16 + (l & 15), slot);
#pragma unroll
      for (int n = 0; n < 4; ++n) bfr[n] = ldsr8(Bs, wc * 64 + n * 16 + (l & 15), slot);
#pragma unroll
      for (int m = 0; m < 4; ++m)
#pragma unroll
        for (int n = 0; n < 4; ++n)
          acc[m][n] = MFMA16(af[m], bfr[n], acc[m][n]);
    }
    __syncthreads();
  }

#pragma unroll
  for (int m = 0; m < 4; ++m) {
    int row = m0 + wr * 64 + m * 16 + ((l >> 4) << 2);
#pragma unroll
    for (int n = 0; n < 4; ++n) {
      int col = n0 + wc * 64 + n * 16 + (l & 15);
#pragma unroll
      for (int r = 0; r < 4; ++r) {
        float v = acc[m][n][r] * scale;
        if (OUT_F32)
          ((float*)Dv)[(size_t)(row + r) * 512 + col] = v;
        else
          ((u16*)Dv)[(size_t)(row + r) * 512 + col] = f2bf(v);
      }
    }
  }
}

// One iteration of the 2-phase pipelined attention loop (8-wave, 128 q-rows/block).
// Bias is loaded DIRECTLY into sacc (MFMA C-init) each iteration — no bias
// register double-buffer. This keeps VGPR <= 64 (occupancy cliff per m69:
// 65+ VGPRs halves waves/SIMD; round-10's 72-VGPR kernel was register-limited
// to 16 waves/CU and latency-bound at 14% MfmaUtil). Loads are L2-resident
// (XCD swizzle) and their latency hides under ds_reads + cross-wave TLP.
__device__ __forceinline__ void attn_iter(
    int kt, const u16* Kc, const u16* Vc, u16* Kn, u16* Vn,
    const u16* __restrict__ K, const u16* __restrict__ Vt,
    const float* bbase, int b, int h, int w, int l, int srow, int sslot,
    const bf16x8 (&qf)[2], u16* Pw, f32x4 (&o_acc)[4], float (&ps)[4]) {
  const bool notlast = (kt < 15);

  // (a) bias loads for THIS tile -> sacc (issued first; latency overlaps ds_reads)
  f32x4 sacc[4];
#pragma unroll
  for (int nf = 0; nf < 4; ++nf)
#pragma unroll
    for (int r = 0; r < 4; ++r)
      sacc[nf][r] = bbase[(size_t)r * SEQ + kt * 64 + nf * 16];

  // (b) issue next tile's K/V staging — HBM/L2 latency hides under compute
  if (notlast) {
    int row = w * 8;  // 8 waves cover 64 rows with one g2l16 each
    g2l16(K + (size_t)(b * SEQ + (kt + 1) * 64 + row + srow) * DIM + h * 64 + sslot * 8,
          &Kn[row * 64]);
    g2l16(Vt + (size_t)(b * 512 + h * 64 + row + srow) * SEQ + (kt + 1) * 64 + sslot * 8,
          &Vn[row * 64]);
  }

  // (c) S = bias + q@k^T
  __builtin_amdgcn_s_setprio(1);
#pragma unroll
  for (int ks = 0; ks < 2; ++ks) {
    int slot = ks * 4 + (l >> 4);
#pragma unroll
    for (int nf = 0; nf < 4; ++nf) {
      bf16x8 kf = ldsr8(Kc, nf * 16 + (l & 15), slot);
      sacc[nf] = MFMA16(qf[ks], kf, sacc[nf]);
    }
  }
  __builtin_amdgcn_s_setprio(0);

  // (d) exp -> P (bf16) to per-wave LDS region (swizzled)
#pragma unroll
  for (int r = 0; r < 4; ++r) {
    int prow = ((l >> 4) << 2) + r;
#pragma unroll
    for (int nf = 0; nf < 4; ++nf) {
      float p = __expf(sacc[nf][r]);
      ps[r] += p;
      int col = nf * 16 + (l & 15);
      int slot = (col >> 3) ^ (prow & 7);
      Pw[prow * 64 + slot * 8 + (col & 7)] = f2bf(p);
    }
  }

  // (e) O += P @ V
  __builtin_amdgcn_s_setprio(1);
#pragma unroll
  for (int ks = 0; ks < 2; ++ks) {
    bf16x8 pf = ldsr8(Pw, l & 15, ks * 4 + (l >> 4));
    int slot = ks * 4 + (l >> 4);
#pragma unroll
    for (int nf = 0; nf < 4; ++nf) {
      bf16x8 vf = ldsr8(Vc, nf * 16 + (l & 15), slot);
      o_acc[nf] = MFMA16(pf, vf, o_acc[nf]);
    }
  }
  __builtin_amdgcn_s_setprio(0);
  __syncthreads();  // next buffers staged + all reads of cur done
}

// Per block: one (b,h,qt), 128 q-rows, 8 waves (each owns 16 q-rows).
// 1-D grid with XCD-aware decode: id%8 = h (8 XCDs <-> 8 heads), b fastest
// within an XCD, qt slowest — each XCD's L2 holds one head's K/V + bias reuse.
// LDS 48KB -> 3 blocks/CU; VGPR <= 64 (see attn_iter comment) -> not reg-limited.
__global__ __launch_bounds__(512)
void attn_kern(const u16* __restrict__ Q, const u16* __restrict__ K,
               const u16* __restrict__ Vt, const float* __restrict__ bias,
               u16* __restrict__ O) {
  __shared__ u16 QPs[128 * 64];  // Q staging (16KB), then per-wave P scratch (8 x 2KB)
  __shared__ u16 K0s[64 * 64], V0s[64 * 64], K1s[64 * 64], V1s[64 * 64];

  const int tid = threadIdx.x;
  const int w = tid >> 6, l = tid & 63;
  const int id = blockIdx.x;
  const int h = id & 7;
  const int b = (id >> 3) & 15;
  const int qt = id >> 7;

  const int srow = l >> 3;
  const int sslot = (l & 7) ^ srow;

  // prologue: stage Q (2 g2l16/wave) + tile0 K/V (1 each/wave)
#pragma unroll
  for (int it = 0; it < 2; ++it) {
    int row = w * 16 + it * 8;
    g2l16(Q + (size_t)(b * SEQ + qt * 128 + row + srow) * DIM + h * 64 + sslot * 8,
          &QPs[row * 64]);
  }
  {
    int row = w * 8;
    g2l16(K + (size_t)(b * SEQ + row + srow) * DIM + h * 64 + sslot * 8, &K0s[row * 64]);
    g2l16(Vt + (size_t)(b * 512 + h * 64 + row + srow) * SEQ + sslot * 8, &V0s[row * 64]);
  }
  const int qrow0 = qt * 128 + w * 16 + ((l >> 4) << 2);
  const float* bbase = bias + ((size_t)h * SEQ + qrow0) * SEQ + (l & 15);
  __syncthreads();

  bf16x8 qf[2];
#pragma unroll
  for (int ks = 0; ks < 2; ++ks)
    qf[ks] = ldsr8(QPs, w * 16 + (l & 15), ks * 4 + (l >> 4));
  u16* Pw = &QPs[w * 16 * 64];  // each wave reads only its own 16 rows

  f32x4 o_acc[4] = {};
  float ps[4] = {};

  for (int kt = 0; kt < 16; kt += 2) {
    attn_iter(kt, K0s, V0s, K1s, V1s, K, Vt, bbase,
              b, h, w, l, srow, sslot, qf, Pw, o_acc, ps);
    attn_iter(kt + 1, K1s, V1s, K0s, V0s, K, Vt, bbase,
              b, h, w, l, srow, sslot, qf, Pw, o_acc, ps);
  }

  float rinv[4];
#pragma unroll
  for (int r = 0; r < 4; ++r) {
    float s = ps[r];
    s += __shfl_xor(s, 1); s += __shfl_xor(s, 2);
    s += __shfl_xor(s, 4); s += __shfl_xor(s, 8);
    rinv[r] = 1.0f / s;
  }
  const int orow0 = b * SEQ + qt * 128 + w * 16 + ((l >> 4) << 2);
#pragma unroll
  for (int nf = 0; nf < 4; ++nf) {
    int col = h * 64 + nf * 16 + (l & 15);
#pragma unroll
    for (int r = 0; r < 4; ++r)
      O[(size_t)(orow0 + r) * DIM + col] = f2bf(o_acc[nf][r] * rinv[r]);
  }
}

extern "C" void kernel_launch(void* const* d_in, const int* in_sizes, int n_in,
                              void* d_out, int out_size, void* d_ws, size_t ws_size,
                              hipStream_t stream) {
  const float* x  = (const float*)d_in[0];
  const float* pb = (const float*)d_in[1];
  const float* Wq = (const float*)d_in[2];
  const float* Wk = (const float*)d_in[3];
  const float* Wv = (const float*)d_in[4];
  const float* Wo = (const float*)d_in[5];

  const size_t MR = (size_t)16384 * 512;  // 8.39M elems (B*N x DIM)

  // Q,K (bf16) live inside d_out (exactly 2*MR*2 bytes). Buffer rotation keeps
  // ws at ~35.7MB: slot0: xb -> Vt ; slot1: Vw -> AO.
  u16* Qw = (u16*)d_out;
  u16* Kw = Qw + MR;

  char* ws = (char*)d_ws;
  u16* slot0 = (u16*)ws; ws += MR * 2;
  u16* slot1 = (u16*)ws; ws += MR * 2;
  u16* wqb = (u16*)ws; ws += 512 * 512 * 2;
  u16* wkb = (u16*)ws; ws += 512 * 512 * 2;
  u16* wvb = (u16*)ws; ws += 512 * 512 * 2;
  u16* wob = (u16*)ws; ws += 512 * 512 * 2;

  u16* xb = slot0;
  u16* Vw = slot1;
  u16* Vt = slot0;   // overwrites xb after it's dead
  u16* AO = slot1;   // overwrites Vw after it's dead

  cvt4<<<2048, 256, 0, stream>>>((const float4*)x, (ushort4*)xb, (int)(MR / 4));
  cvtw<<<dim3(64, 4), 256, 0, stream>>>((const float4*)Wq, (const float4*)Wk,
                                        (const float4*)Wv, (const float4*)Wo,
                                        (ushort4*)wqb, (ushort4*)wkb,
                                        (ushort4*)wvb, (ushort4*)wob);

  gemm_bt<0><<<dim3(12, 128), 256, 0, stream>>>(xb, wqb, wkb, wvb, Qw, Kw, Vw, 0.125f);

  transpose_v<<<dim3(8, 16, 16), 256, 0, stream>>>(Vw, Vt);

  attn_kern<<<dim3(1024), 512, 0, stream>>>(Qw, Kw, Vt, pb, AO);

  gemm_bt<1><<<dim3(4, 128), 256, 0, stream>>>(AO, wob, wob, wob, d_out, d_out, d_out, 1.0f);
}